// Round 2
// baseline (451.319 us; speedup 1.0000x reference)
//
#include <hip/hip_runtime.h>
#include <hip/hip_bf16.h>

typedef __bf16 bf16_t;
typedef __bf16 bf16x8 __attribute__((ext_vector_type(8)));
typedef float f32x4 __attribute__((ext_vector_type(4)));

__device__ __forceinline__ float ldin(const void* p, long i, int isbf) {
  if (isbf) {
    unsigned short u = ((const unsigned short*)p)[i];
    unsigned int w = ((unsigned int)u) << 16;
    float f; __builtin_memcpy(&f, &w, 4); return f;
  }
  return ((const float*)p)[i];
}

__device__ __forceinline__ bf16_t f2b(float f) {
  unsigned int u; __builtin_memcpy(&u, &f, 4);
  u += 0x7FFFu + ((u >> 16) & 1u);
  unsigned short h = (unsigned short)(u >> 16);
  bf16_t r; __builtin_memcpy(&r, &h, 2); return r;
}

__device__ __forceinline__ float b2f(bf16_t b) {
  unsigned short h; __builtin_memcpy(&h, &b, 2);
  unsigned int u = ((unsigned int)h) << 16;
  float f; __builtin_memcpy(&f, &u, 4); return f;
}

__device__ __forceinline__ float bb2f(unsigned short h) {
  unsigned int u = ((unsigned int)h) << 16;
  float f; __builtin_memcpy(&f, &u, 4); return f;
}

__device__ __forceinline__ unsigned short bbits(bf16_t b) {
  unsigned short h; __builtin_memcpy(&h, &b, 2); return h;
}

__device__ __forceinline__ void ld4(const void* p, long i, int isbf, float* v) {
  if (isbf) {
    ushort4 u = *(const ushort4*)((const unsigned short*)p + i);
    v[0] = bb2f(u.x); v[1] = bb2f(u.y); v[2] = bb2f(u.z); v[3] = bb2f(u.w);
  } else {
    float4 f = *(const float4*)((const float*)p + i);
    v[0] = f.x; v[1] = f.y; v[2] = f.z; v[3] = f.w;
  }
}

__device__ __forceinline__ f32x4 mfma(bf16x8 a, bf16x8 b, f32x4 c) {
  return __builtin_amdgcn_mfma_f32_16x16x32_bf16(a, b, c, 0, 0, 0);
}

// ---- async global->LDS DMA (16B per lane, LDS dest = wave base + lane*16) ----
__device__ __forceinline__ void gll16(const void* g, void* l) {
  __builtin_amdgcn_global_load_lds(
      reinterpret_cast<const __attribute__((address_space(1))) unsigned int*>(
          reinterpret_cast<unsigned long long>(g)),
      reinterpret_cast<__attribute__((address_space(3))) unsigned int*>(
          (unsigned int)reinterpret_cast<unsigned long long>(l)),
      16, 0, 0);
}

// stage one [32 rows][128 cols] bf16 chunk; global row-major with row stride grs
// (elements). Source pre-swizzled (colblk ^ (row&7)) so LDS is linear but reads
// use the same XOR involution (G21 both-sides rule). 2 instrs per wave.
__device__ __forceinline__ void stage8(const bf16_t* gbase, int grs, bf16_t* lds,
                                       int wv, int lane) {
  int sub = lane >> 4, cb = lane & 15;
  #pragma unroll
  for (int j = 0; j < 2; ++j) {
    int row = wv * 8 + j * 4 + sub;
    int scb = cb ^ (row & 7);
    gll16(gbase + (long)row * grs + scb * 8, lds + (wv * 8 + j * 4) * 128);
  }
}

// counted-vmcnt barrier protocol (T3+T4): never drain vmcnt in the loop
template <int N>
__device__ __forceinline__ void waitbar() {
  asm volatile("s_waitcnt vmcnt(%0) lgkmcnt(0)" ::"n"(N) : "memory");
  __builtin_amdgcn_sched_barrier(0);
  __builtin_amdgcn_s_barrier();
  __builtin_amdgcn_sched_barrier(0);
}
__device__ __forceinline__ void relbar() {
  __builtin_amdgcn_sched_barrier(0);
  __builtin_amdgcn_s_barrier();
  __builtin_amdgcn_sched_barrier(0);
}
__device__ __forceinline__ void lgkbar() {
  asm volatile("s_waitcnt lgkmcnt(0)" ::: "memory");
  __builtin_amdgcn_sched_barrier(0);
  __builtin_amdgcn_s_barrier();
  __builtin_amdgcn_sched_barrier(0);
}

// ---- dtype detector ----
__global__ void kdetect(const unsigned int* x, int* flag) {
  __shared__ int cnt;
  if (threadIdx.x == 0) cnt = 0;
  __syncthreads();
  int local = 0;
  for (int k = 0; k < 4; ++k) {
    unsigned int u = x[threadIdx.x * 4 + k];
    unsigned int e = (u >> 7) & 0xFFu;
    if (e >= 116u && e <= 133u) local++;
  }
  atomicAdd(&cnt, local);
  __syncthreads();
  if (threadIdx.x == 0) *flag = (cnt > 512) ? 1 : 0;
}

// ---- K0: weight conversion + BN folding ----
__global__ void k0(const void* thw_f, const void* phw, const void* gw, const void* ww_f,
                   const void* wb, const void* gma, const void* bta, const void* mean,
                   const void* var, bf16_t* thwb, bf16_t* phwb, bf16_t* gwb, bf16_t* wwb,
                   float* scw, float* shw, const int* flag) {
  int isbf = *flag;
  int i = blockIdx.x * 256 + threadIdx.x;
  thwb[i] = f2b(ldin(thw_f, i, isbf));
  phwb[i] = f2b(ldin(phw, i, isbf));
  gwb[i]  = f2b(ldin(gw, i, isbf));
  wwb[i]  = f2b(ldin(ww_f, i, isbf));
  if (i < 256) {
    float s = ldin(gma, i, isbf) * rsqrtf(ldin(var, i, isbf) + 1e-5f);
    scw[i] = s;
    shw[i] = (ldin(wb, i, isbf) - ldin(mean, i, isbf)) * s + ldin(bta, i, isbf);
  }
}

// ---- K1: phi + g convs (shared A), register maxpool ----
// sX: [64][256] no pad, XOR swizzle swz(m)=(((m>>2)^m)&7)<<3 -> conflict-free
// scalar transposed writes (2-way merged) and spread b128 reads.
__global__ __launch_bounds__(256) void k1(const void* xin, const bf16_t* phwb,
    const bf16_t* gwb, const void* phb, const void* gbb,
    bf16_t* phiH, bf16_t* phiL, bf16_t* gT, const int* flag) {
  int isbf = *flag;
  int wg = blockIdx.x;
  int tile = wg >> 4, j = wg & 15;
  int bi = tile >> 4, t16 = tile & 15, ty = t16 >> 2, tx = t16 & 3;
  long xb = (long)bi * 256 * 16384 + (long)(ty * 32 + 2 * j) * 128 + tx * 32;

  __shared__ __align__(16) bf16_t sX[64 * 256];

  int tid = threadIdx.x, lane = tid & 63, wv = tid >> 6;
  int qd = lane >> 4, ln = lane & 15, kq = qd * 8;

  {
    int mq = tid & 15, c0 = tid >> 4;
    int ma = (mq >> 3) * 128 + (mq & 7) * 4;
    #pragma unroll
    for (int it = 0; it < 16; ++it) {
      int c = it * 16 + c0;
      float v[4];
      ld4(xin, xb + (long)c * 16384 + ma, isbf, v);
      #pragma unroll
      for (int r = 0; r < 4; ++r) {
        int m = mq * 4 + r;
        int s = (((m >> 2) ^ m) & 7) << 3;
        sX[m * 256 + (c ^ s)] = f2b(v[r]);
      }
    }
  }
  __syncthreads();

  f32x4 accP[4][2], accG[4][2];
  for (int mb = 0; mb < 4; ++mb) {
    int row = mb * 16 + ln;
    int s = (((row >> 2) ^ row) & 7) << 3;
    bf16x8 af[8];
    #pragma unroll
    for (int c = 0; c < 8; ++c) af[c] = *(const bf16x8*)(sX + row * 256 + ((c * 32 + kq) ^ s));
    #pragma unroll
    for (int h = 0; h < 2; ++h) {
      int nt = wv + h * 4;
      const bf16_t* Bp = phwb + (nt * 16 + ln) * 256;
      const bf16_t* Bg = gwb + (nt * 16 + ln) * 256;
      f32x4 ap = {0.f,0.f,0.f,0.f}, ag = {0.f,0.f,0.f,0.f};
      #pragma unroll
      for (int c = 0; c < 8; ++c) {
        int ko = c * 32 + kq;
        ap = mfma(af[c], *(const bf16x8*)(Bp + ko), ap);
        ag = mfma(af[c], *(const bf16x8*)(Bg + ko), ag);
      }
      accP[mb][h] = ap; accG[mb][h] = ag;
    }
  }

  for (int mb2 = 0; mb2 < 2; ++mb2)
    #pragma unroll
    for (int h = 0; h < 2; ++h) {
      int o = (wv + h * 4) * 16 + ln;
      float pb = ldin(phb, o, isbf), gb2 = ldin(gbb, o, isbf);
      #pragma unroll
      for (int r = 0; r < 4; r += 2) {
        float v = fmaxf(fmaxf(accP[mb2][h][r], accP[mb2][h][r + 1]),
                        fmaxf(accP[mb2 + 2][h][r], accP[mb2 + 2][h][r + 1]));
        float u = fmaxf(fmaxf(accG[mb2][h][r], accG[mb2][h][r + 1]),
                        fmaxf(accG[mb2 + 2][h][r], accG[mb2 + 2][h][r + 1]));
        int cp = mb2 * 8 + qd * 2 + (r >> 1);
        int kpos = j * 16 + cp;
        float pv = v + pb;
        bf16_t hi = f2b(pv);
        phiH[(long)tile * 32768 + kpos * 128 + o] = hi;
        phiL[(long)tile * 32768 + kpos * 128 + o] = f2b(pv - b2f(hi));
        gT[(long)tile * 32768 + (long)o * 256 + kpos] = f2b(u + gb2);
      }
    }
}

// ---- K2: in-kernel theta, fully pipelined async staging, register softmax ----
// LDS map (49152 B):
//  @0     sX [32][512] hi|lo (theta phase only)
//         aliases: phi 16KB slabs A@0 / B@16384 (H@+0, L@+8192 bytes)
//                  8KB slots s0@0 / s1@8192 (g, ww chunks)
//                  sY @16384 (8KB), sredM @24576, sredS @24832
//  @32768 sTh [32][128]; @40960 sTl [32][128]; sF [32][256] aliases @32768
__global__ __launch_bounds__(256, 3) void k2(const void* xin, const bf16_t* thwb,
    const void* thb, const bf16_t* phiH, const bf16_t* phiL, const bf16_t* gT,
    const bf16_t* wwb, const float* sc, const float* sh, void* outv, const int* flag) {
  int isbf = *flag;
  int wg = (blockIdx.x & 7) * 512 + (blockIdx.x >> 3);  // XCD swizzle (4096%8==0)
  int tile = wg >> 5, qb = wg & 31;
  int bi = tile >> 4, t16 = tile & 15, ty = t16 >> 2, tx = t16 & 3;
  long xbase = (long)bi * 256 * 16384 + (long)(ty * 32 + qb) * 128 + tx * 32;

  __shared__ __align__(16) char smem[49152];
  bf16_t* sX  = (bf16_t*)smem;
  bf16_t* sTh = (bf16_t*)(smem + 32768);
  bf16_t* sTl = (bf16_t*)(smem + 40960);
  bf16_t* sF  = (bf16_t*)(smem + 32768);
  bf16_t* sY  = (bf16_t*)(smem + 16384);
  float* sredM = (float*)(smem + 24576);
  float* sredS = (float*)(smem + 24832);

  int tid = threadIdx.x, lane = tid & 63, wv = tid >> 6;
  int qd = lane >> 4, ln = lane & 15, kq = qd * 8;
  int ms = wv >> 1, half = wv & 1;
  int m0 = ms * 16 + qd * 4;

  // ---- x slab -> sX [hi|lo], swizzled (conflict-free scalar writes) ----
  {
    int wq = tid & 7, c0 = tid >> 3;
    #pragma unroll
    for (int it = 0; it < 8; ++it) {
      int c = it * 32 + c0;
      float v[4];
      ld4(xin, xbase + (long)c * 16384 + wq * 4, isbf, v);
      #pragma unroll
      for (int r = 0; r < 4; ++r) {
        int m = wq * 4 + r;
        int s = (((m >> 2) ^ m) & 7) << 3;
        int cs = c ^ s;
        bf16_t hi = f2b(v[r]);
        sX[m * 512 + cs] = hi;
        sX[m * 512 + 256 + cs] = f2b(v[r] - b2f(hi));
      }
    }
  }
  lgkbar();

  // ---- theta = Xhi @ thw, hi/lo split into sTh/sTl ----
  {
    bf16x8 Axf[8];
    #pragma unroll
    for (int t = 0; t < 4; ++t) {
      int tms = t >> 1, tns = (t & 1) * 4 + wv;
      if ((t & 1) == 0) {
        int row = tms * 16 + ln;
        int s = (((row >> 2) ^ row) & 7) << 3;
        #pragma unroll
        for (int c = 0; c < 8; ++c)
          Axf[c] = *(const bf16x8*)(sX + row * 512 + ((c * 32 + kq) ^ s));
      }
      const bf16_t* B = thwb + (tns * 16 + ln) * 256;
      f32x4 a = {0.f,0.f,0.f,0.f};
      #pragma unroll
      for (int c = 0; c < 8; ++c) a = mfma(Axf[c], *(const bf16x8*)(B + c * 32 + kq), a);
      float bias = ldin(thb, tns * 16 + ln, isbf);
      #pragma unroll
      for (int r = 0; r < 4; ++r) {
        float v = a[r] + bias;
        bf16_t hi = f2b(v);
        int mrow = tms * 16 + qd * 4 + r;
        int col = (tns * 16 + ln) ^ ((mrow & 7) << 3);
        sTh[mrow * 128 + col] = hi;
        sTl[mrow * 128 + col] = f2b(v - b2f(hi));
      }
    }
  }

  // ---- residual extract (hi+lo) before sX is overwritten by staging ----
  f32x4 xres[8];
  #pragma unroll
  for (int u = 0; u < 8; ++u) {
    int o = (2 * u + half) * 16 + ln;
    f32x4 xr;
    #pragma unroll
    for (int r = 0; r < 4; ++r) {
      int row = m0 + r;
      int s = (((row >> 2) ^ row) & 7) << 3;
      int cs = o ^ s;
      xr[r] = b2f(sX[row * 512 + cs]) + b2f(sX[row * 512 + 256 + cs]);
    }
    xres[u] = xr;
  }
  lgkbar();   // sX dead; sTh/sTl published

  // theta A-frags into registers (sF may alias sTh/sTl later)
  bf16x8 Ah[4], Al[4];
  {
    int row = ms * 16 + ln, sw = (row & 7) << 3;
    #pragma unroll
    for (int c = 0; c < 4; ++c) {
      Ah[c] = *(const bf16x8*)(sTh + row * 128 + ((c * 32 + kq) ^ sw));
      Al[c] = *(const bf16x8*)(sTl + row * 128 + ((c * 32 + kq) ^ sw));
    }
  }

  const bf16_t* PH = phiH + (long)tile * 32768;
  const bf16_t* PL = phiL + (long)tile * 32768;
  const bf16_t* GG = gT + (long)tile * 32768;
  bf16_t* slabA = (bf16_t*)smem;
  bf16_t* slabB = (bf16_t*)(smem + 16384);
  bf16_t* s8a = (bf16_t*)smem;
  bf16_t* s8b = (bf16_t*)(smem + 8192);

  // prologue: phi chunks 0,1 in flight (4 DMA ops each)
  stage8(PH, 128, slabA, wv, lane);
  stage8(PL, 128, slabA + 4096, wv, lane);
  stage8(PH + 4096, 128, slabB, wv, lane);
  stage8(PL + 4096, 128, slabB + 4096, wv, lane);

  int brow = half * 16 + ln;
  int bsw = (brow & 7) << 3;

  // ---- S = theta @ phi^T, 8 chunks of 32 k-rows, double-buffered ----
  f32x4 S[8];
  #pragma unroll
  for (int c = 0; c < 8; ++c) {
    if (c < 7) waitbar<4>(); else waitbar<2>();
    const bf16_t* Bh = ((c & 1) ? slabB : slabA) + brow * 128;
    const bf16_t* Bl = Bh + 4096;
    f32x4 a = {0.f,0.f,0.f,0.f};
    #pragma unroll
    for (int kk = 0; kk < 4; ++kk) {
      int co = (kk * 32 + kq) ^ bsw;
      bf16x8 bh = *(const bf16x8*)(Bh + co);
      bf16x8 bl = *(const bf16x8*)(Bl + co);
      a = mfma(Ah[kk], bl, a);
      a = mfma(Al[kk], bh, a);
      a = mfma(Ah[kk], bh, a);
    }
    S[c] = a;
    relbar();
    if (c < 6) {
      bf16_t* dst = (c & 1) ? slabB : slabA;
      stage8(PH + (c + 2) * 4096, 128, dst, wv, lane);
      stage8(PL + (c + 2) * 4096, 128, dst + 4096, wv, lane);
    } else if (c == 6) {
      stage8(GG, 256, s8a, wv, lane);            // g(ib0,kh0)
    } else {
      stage8(GG + 128, 256, s8b, wv, lane);      // g(ib0,kh1) — hides under softmax
    }
  }

  // ---- register softmax ----
  float Mr[4], Sr[4], inv4[4];
  #pragma unroll
  for (int r = 0; r < 4; ++r) {
    float m = S[0][r];
    #pragma unroll
    for (int t = 1; t < 8; ++t) m = fmaxf(m, S[t][r]);
    #pragma unroll
    for (int d = 1; d < 16; d <<= 1) m = fmaxf(m, __shfl_xor(m, d, 64));
    Mr[r] = m;
  }
  if (ln == 0) {
    #pragma unroll
    for (int r = 0; r < 4; ++r) sredM[(m0 + r) * 2 + half] = Mr[r];
  }
  lgkbar();
  #pragma unroll
  for (int r = 0; r < 4; ++r) Mr[r] = fmaxf(Mr[r], sredM[(m0 + r) * 2 + (half ^ 1)]);
  #pragma unroll
  for (int r = 0; r < 4; ++r) {
    float s = 0.f;
    #pragma unroll
    for (int t = 0; t < 8; ++t) { float e = __expf(S[t][r] - Mr[r]); S[t][r] = e; s += e; }
    #pragma unroll
    for (int d = 1; d < 16; d <<= 1) s += __shfl_xor(s, d, 64);
    Sr[r] = s;
  }
  if (ln == 0) {
    #pragma unroll
    for (int r = 0; r < 4; ++r) sredS[(m0 + r) * 2 + half] = Sr[r];
  }
  lgkbar();
  #pragma unroll
  for (int r = 0; r < 4; ++r) inv4[r] = 1.f / (Sr[r] + sredS[(m0 + r) * 2 + (half ^ 1)]);

  // F -> sF (aliases sTh/sTl; theta frags live in regs)
  #pragma unroll
  for (int c = 0; c < 8; ++c) {
    int n = c * 32 + half * 16 + ln;
    #pragma unroll
    for (int r = 0; r < 4; ++r) {
      int row = m0 + r;
      sF[row * 256 + (n ^ ((row & 7) << 3))] = f2b(S[c][r] * inv4[r]);
    }
  }
  lgkbar();

  bf16x8 Fa[8];
  {
    int row = ms * 16 + ln, sw = (row & 7) << 3;
    #pragma unroll
    for (int c = 0; c < 8; ++c)
      Fa[c] = *(const bf16x8*)(sF + row * 256 + ((c * 32 + kq) ^ sw));
  }

  // ---- y = F @ g: 8 chunks (ib 0..3 x kh 0..1), 8KB slots ----
  f32x4 ya = {0.f,0.f,0.f,0.f};
  #pragma unroll
  for (int u = 0; u < 8; ++u) {
    int ib = u >> 1, kh = u & 1;
    waitbar<2>();
    const bf16_t* Bg = ((u & 1) ? s8b : s8a) + brow * 128;
    if (kh == 0) ya = (f32x4){0.f,0.f,0.f,0.f};
    #pragma unroll
    for (int kk = 0; kk < 4; ++kk)
      ya = mfma(Fa[kh * 4 + kk], *(const bf16x8*)(Bg + ((kk * 32 + kq) ^ bsw)), ya);
    if (kh == 1) {
      #pragma unroll
      for (int r = 0; r < 4; ++r) {
        int row = m0 + r;
        int col = ib * 32 + half * 16 + ln;
        sY[row * 128 + (col ^ ((row & 7) << 3))] = f2b(ya[r]);
      }
    }
    relbar();
    if (u < 6) {
      int u2 = u + 2;
      stage8(GG + (u2 >> 1) * 8192 + (u2 & 1) * 128, 256,
             (u2 & 1) ? s8b : s8a, wv, lane);
    } else if (u == 6) {
      stage8(wwb, 128, s8a, wv, lane);           // ww chunk 0
    } else {
      stage8(wwb + 4096, 128, s8b, wv, lane);    // ww chunk 1
    }
  }

  // ---- wy = y @ ww^T + BN + residual (accumulated into xres regs) ----
  bf16x8 Ya[4];
  #pragma unroll
  for (int u = 0; u < 8; ++u) {
    if (u < 7) waitbar<2>(); else waitbar<0>();
    if (u == 0) {
      int row = ms * 16 + ln, sw = (row & 7) << 3;
      #pragma unroll
      for (int kk = 0; kk < 4; ++kk)
        Ya[kk] = *(const bf16x8*)(sY + row * 128 + ((kk * 32 + kq) ^ sw));
    }
    const bf16_t* Bw = ((u & 1) ? s8b : s8a) + brow * 128;
    f32x4 a = {0.f,0.f,0.f,0.f};
    #pragma unroll
    for (int kk = 0; kk < 4; ++kk)
      a = mfma(Ya[kk], *(const bf16x8*)(Bw + ((kk * 32 + kq) ^ bsw)), a);
    int o = u * 32 + half * 16 + ln;
    float s2 = sc[o], hh = sh[o];
    #pragma unroll
    for (int r = 0; r < 4; ++r) xres[u][r] = a[r] * s2 + hh + xres[u][r];
    relbar();
    if (u < 6) stage8(wwb + (u + 2) * 4096, 128, (u & 1) ? s8b : s8a, wv, lane);
  }

  // ---- final stores ----
  long ob = (long)tile * 262144 + qb * 32 + m0;
  #pragma unroll
  for (int u = 0; u < 8; ++u) {
    int o = u * 32 + half * 16 + ln;
    long oi = ob + (long)o * 1024;
    if (isbf) {
      unsigned short uu[4];
      #pragma unroll
      for (int r = 0; r < 4; ++r) uu[r] = bbits(f2b(xres[u][r]));
      __builtin_memcpy((unsigned short*)outv + oi, uu, 8);
    } else {
      float vv[4];
      #pragma unroll
      for (int r = 0; r < 4; ++r) vv[r] = xres[u][r];
      __builtin_memcpy((float*)outv + oi, vv, 16);
    }
  }
}

extern "C" void kernel_launch(void* const* d_in, const int* in_sizes, int n_in,
                              void* d_out, int out_size, void* d_ws, size_t ws_size,
                              hipStream_t stream) {
  (void)in_sizes; (void)n_in; (void)out_size; (void)ws_size;
  const void* x    = d_in[0];
  const void* thwf = d_in[1];
  const void* thb  = d_in[2];
  const void* phw  = d_in[3];
  const void* phb  = d_in[4];
  const void* gwf  = d_in[5];
  const void* gbb  = d_in[6];
  const void* wwf  = d_in[7];
  const void* wb   = d_in[8];
  const void* gma  = d_in[9];
  const void* bta  = d_in[10];
  const void* mn   = d_in[11];
  const void* vr   = d_in[12];

  char* ws = (char*)d_ws;
  bf16_t* thwb = (bf16_t*)(ws);                    // 65536
  bf16_t* phwb = (bf16_t*)(ws + 65536);            // 65536
  bf16_t* gwb  = (bf16_t*)(ws + 131072);           // 65536
  bf16_t* wwb  = (bf16_t*)(ws + 196608);           // 65536
  float*  sc   = (float*)(ws + 262144);            // 1024
  float*  sh   = (float*)(ws + 263168);            // 1024
  int*    flag = (int*)(ws + 264192);              // 256
  bf16_t* phiH = (bf16_t*)(ws + 264448);           // 8388608  [tile][k][i]
  bf16_t* phiL = (bf16_t*)(ws + 264448 + 8388608); // 8388608
  bf16_t* gT   = (bf16_t*)(ws + 264448 + 16777216);// 8388608  [tile][i][k]

  kdetect<<<1, 256, 0, stream>>>((const unsigned int*)x, flag);
  k0<<<128, 256, 0, stream>>>(thwf, phw, gwf, wwf, wb, gma, bta, mn, vr,
                              thwb, phwb, gwb, wwb, sc, sh, flag);
  k1<<<2048, 256, 0, stream>>>(x, phwb, gwb, phb, gbb, phiH, phiL, gT, flag);
  k2<<<4096, 256, 0, stream>>>(x, thwb, thb, phiH, phiL, gT, wwb, sc, sh,
                               d_out, flag);
}

// Round 4
// 436.912 us; speedup vs baseline: 1.0330x; 1.0330x over previous
//
#include <hip/hip_runtime.h>
#include <hip/hip_bf16.h>

typedef __bf16 bf16_t;
typedef __bf16 bf16x8 __attribute__((ext_vector_type(8)));
typedef float f32x4 __attribute__((ext_vector_type(4)));

#define LDT 136   // sTh/sTl/sY rows (128 + 8)
#define LDF 264   // sF rows (256 + 8)
#define LDP 136   // staged phi/ww rows (128 + 8)
#define LDG 264   // staged g rows (256 + 8)

__device__ __forceinline__ float ldin(const void* p, long i, int isbf) {
  if (isbf) {
    unsigned short u = ((const unsigned short*)p)[i];
    unsigned int w = ((unsigned int)u) << 16;
    float f; __builtin_memcpy(&f, &w, 4); return f;
  }
  return ((const float*)p)[i];
}

__device__ __forceinline__ bf16_t f2b(float f) {
  unsigned int u; __builtin_memcpy(&u, &f, 4);
  u += 0x7FFFu + ((u >> 16) & 1u);
  unsigned short h = (unsigned short)(u >> 16);
  bf16_t r; __builtin_memcpy(&r, &h, 2); return r;
}

__device__ __forceinline__ float b2f(bf16_t b) {
  unsigned short h; __builtin_memcpy(&h, &b, 2);
  unsigned int u = ((unsigned int)h) << 16;
  float f; __builtin_memcpy(&f, &u, 4); return f;
}

__device__ __forceinline__ float bb2f(unsigned short h) {
  unsigned int u = ((unsigned int)h) << 16;
  float f; __builtin_memcpy(&f, &u, 4); return f;
}

__device__ __forceinline__ unsigned short bbits(bf16_t b) {
  unsigned short h; __builtin_memcpy(&h, &b, 2); return h;
}

__device__ __forceinline__ void ld4(const void* p, long i, int isbf, float* v) {
  if (isbf) {
    ushort4 u = *(const ushort4*)((const unsigned short*)p + i);
    v[0] = bb2f(u.x); v[1] = bb2f(u.y); v[2] = bb2f(u.z); v[3] = bb2f(u.w);
  } else {
    float4 f = *(const float4*)((const float*)p + i);
    v[0] = f.x; v[1] = f.y; v[2] = f.z; v[3] = f.w;
  }
}

__device__ __forceinline__ f32x4 mfma(bf16x8 a, bf16x8 b, f32x4 c) {
  return __builtin_amdgcn_mfma_f32_16x16x32_bf16(a, b, c, 0, 0, 0);
}

// ---- dtype detector ----
__global__ void kdetect(const unsigned int* x, int* flag) {
  __shared__ int cnt;
  if (threadIdx.x == 0) cnt = 0;
  __syncthreads();
  int local = 0;
  for (int k = 0; k < 4; ++k) {
    unsigned int u = x[threadIdx.x * 4 + k];
    unsigned int e = (u >> 7) & 0xFFu;
    if (e >= 116u && e <= 133u) local++;
  }
  atomicAdd(&cnt, local);
  __syncthreads();
  if (threadIdx.x == 0) *flag = (cnt > 512) ? 1 : 0;
}

// ---- K0: weight conversion + BN folding ----
__global__ void k0(const void* thw_f, const void* phw, const void* gw, const void* ww_f,
                   const void* wb, const void* gma, const void* bta, const void* mean,
                   const void* var, bf16_t* thwb, bf16_t* phwb, bf16_t* gwb, bf16_t* wwb,
                   float* scw, float* shw, const int* flag) {
  int isbf = *flag;
  int i = blockIdx.x * 256 + threadIdx.x;
  thwb[i] = f2b(ldin(thw_f, i, isbf));
  phwb[i] = f2b(ldin(phw, i, isbf));
  gwb[i]  = f2b(ldin(gw, i, isbf));
  wwb[i]  = f2b(ldin(ww_f, i, isbf));
  if (i < 256) {
    float s = ldin(gma, i, isbf) * rsqrtf(ldin(var, i, isbf) + 1e-5f);
    scw[i] = s;
    shw[i] = (ldin(wb, i, isbf) - ldin(mean, i, isbf)) * s + ldin(bta, i, isbf);
  }
}

// ---- K1: phi + g convs, B-frags hoisted in regs, coalesced 16B stores ----
__global__ __launch_bounds__(256) void k1(const void* xin, const bf16_t* phwb,
    const bf16_t* gwb, const void* phb, const void* gbb,
    bf16_t* phiH, bf16_t* phiL, bf16_t* gT, const int* flag) {
  int isbf = *flag;
  int wg = blockIdx.x;
  int tile = wg >> 4, j = wg & 15;
  int bi = tile >> 4, t16 = tile & 15, ty = t16 >> 2, tx = t16 & 3;
  long xb = (long)bi * 256 * 16384 + (long)(ty * 32 + 2 * j) * 128 + tx * 32;

  __shared__ __align__(16) bf16_t sX[64 * 256];    // swizzled X^T, 32KB
  __shared__ __align__(16) bf16_t sPoH[16 * 136];  // pooled phi hi [cp][o]
  __shared__ __align__(16) bf16_t sPoL[16 * 136];  // pooled phi lo
  __shared__ __align__(16) bf16_t sGo[128 * 24];   // pooled g [o][cp], 48B rows

  int tid = threadIdx.x, lane = tid & 63, wv = tid >> 6;
  int qd = lane >> 4, ln = lane & 15, kq = qd * 8;

  // prefetch h=0 B-frags before staging (latency hidden under x loads)
  bf16x8 Bp[8], Bg[8];
  {
    const bf16_t* bp = phwb + (wv * 16 + ln) * 256;
    const bf16_t* bg = gwb + (wv * 16 + ln) * 256;
    #pragma unroll
    for (int c = 0; c < 8; ++c) {
      Bp[c] = *(const bf16x8*)(bp + c * 32 + kq);
      Bg[c] = *(const bf16x8*)(bg + c * 32 + kq);
    }
  }

  // x -> sX (transposed, bf16, XOR-swizzled rows)
  {
    int mq = tid & 15, c0 = tid >> 4;
    int ma = (mq >> 3) * 128 + (mq & 7) * 4;
    #pragma unroll
    for (int it = 0; it < 16; ++it) {
      int c = it * 16 + c0;
      float v[4];
      ld4(xin, xb + (long)c * 16384 + ma, isbf, v);
      #pragma unroll
      for (int r = 0; r < 4; ++r) {
        int m = mq * 4 + r;
        int s = (((m >> 2) ^ m) & 7) << 3;
        sX[m * 256 + (c ^ s)] = f2b(v[r]);
      }
    }
  }
  __syncthreads();

  #pragma unroll
  for (int h = 0; h < 2; ++h) {
    if (h == 1) {
      const bf16_t* bp = phwb + ((wv + 4) * 16 + ln) * 256;
      const bf16_t* bg = gwb + ((wv + 4) * 16 + ln) * 256;
      #pragma unroll
      for (int c = 0; c < 8; ++c) {
        Bp[c] = *(const bf16x8*)(bp + c * 32 + kq);
        Bg[c] = *(const bf16x8*)(bg + c * 32 + kq);
      }
    }
    f32x4 accP[4], accG[4];
    #pragma unroll
    for (int mb = 0; mb < 4; ++mb) {
      int row = mb * 16 + ln;
      int s = (((row >> 2) ^ row) & 7) << 3;
      bf16x8 af[8];
      #pragma unroll
      for (int c = 0; c < 8; ++c)
        af[c] = *(const bf16x8*)(sX + row * 256 + ((c * 32 + kq) ^ s));
      f32x4 ap = {0.f,0.f,0.f,0.f}, ag = {0.f,0.f,0.f,0.f};
      #pragma unroll
      for (int c = 0; c < 8; ++c) {
        ap = mfma(af[c], Bp[c], ap);
        ag = mfma(af[c], Bg[c], ag);
      }
      accP[mb] = ap; accG[mb] = ag;
    }
    // 2x2 register maxpool -> LDS staging (identical math/order to before)
    int o = (wv + h * 4) * 16 + ln;
    float pb = ldin(phb, o, isbf), gb2 = ldin(gbb, o, isbf);
    #pragma unroll
    for (int mb2 = 0; mb2 < 2; ++mb2)
      #pragma unroll
      for (int r = 0; r < 4; r += 2) {
        float v = fmaxf(fmaxf(accP[mb2][r], accP[mb2][r + 1]),
                        fmaxf(accP[mb2 + 2][r], accP[mb2 + 2][r + 1]));
        float u = fmaxf(fmaxf(accG[mb2][r], accG[mb2][r + 1]),
                        fmaxf(accG[mb2 + 2][r], accG[mb2 + 2][r + 1]));
        int cp = mb2 * 8 + qd * 2 + (r >> 1);
        float pv = v + pb;
        bf16_t hi = f2b(pv);
        sPoH[cp * 136 + o] = hi;
        sPoL[cp * 136 + o] = f2b(pv - b2f(hi));
        sGo[o * 24 + cp] = f2b(u + gb2);
      }
  }
  __syncthreads();

  // coalesced 16B/lane global stores
  {
    int kp = tid >> 4, seg = tid & 15;
    long base = (long)tile * 32768 + (long)(j * 16 + kp) * 128 + seg * 8;
    *(uint4*)(phiH + base) = *(const uint4*)(sPoH + kp * 136 + seg * 8);
    *(uint4*)(phiL + base) = *(const uint4*)(sPoL + kp * 136 + seg * 8);
  }
  {
    int o = tid >> 1, sg = tid & 1;
    *(uint4*)(gT + (long)tile * 32768 + (long)o * 256 + j * 16 + sg * 8) =
        *(const uint4*)(sGo + o * 24 + sg * 8);
  }
}

// ---- K2: r1 structure (reg-prefetch + __syncthreads) + swizzled sX + XCD swizzle ----
__global__ __launch_bounds__(256, 3) void k2(const void* xin, const bf16_t* thwb,
    const void* thb, const bf16_t* phiH, const bf16_t* phiL, const bf16_t* gT,
    const bf16_t* wwb, const float* sc, const float* sh, void* outv, const int* flag) {
  int isbf = *flag;
  int wg = (blockIdx.x & 7) * 512 + (blockIdx.x >> 3);
  int tile = wg >> 5, qb = wg & 31;
  int bi = tile >> 4, t16 = tile & 15, ty = t16 >> 2, tx = t16 & 3;
  long xbase = (long)bi * 256 * 16384 + (long)(ty * 32 + qb) * 128 + tx * 32;

  __shared__ __align__(16) char smem[51200];
  bf16_t* sX   = (bf16_t*)smem;            // [32][512] hi|lo swizzled
  bf16_t* sPh  = (bf16_t*)smem;            // staging: phi hi [32][136]
  bf16_t* sPl  = (bf16_t*)(smem + 8704);   //          phi lo [32][136]
  bf16_t* sG   = (bf16_t*)smem;            //          g [32][264]
  bf16_t* sW   = (bf16_t*)smem;            //          ww [64][136]
  bf16_t* sY   = (bf16_t*)(smem + 17408);  // [32][136]
  bf16_t* sTh  = (bf16_t*)(smem + 33280);  // [32][136]
  bf16_t* sTl  = (bf16_t*)(smem + 41984);  // [32][136]
  bf16_t* sF   = (bf16_t*)(smem + 33280);  // [32][264] alias sTh/sTl
  float* sredM = (float*)(smem + 50688);
  float* sredS = (float*)(smem + 50944);

  int tid = threadIdx.x, lane = tid & 63, wv = tid >> 6;
  int qd = lane >> 4, ln = lane & 15, kq = qd * 8;
  int ms = wv >> 1, half = wv & 1;
  int m0 = ms * 16 + qd * 4;

  // ---- x slab -> sX [hi|lo], swizzled ----
  {
    int wq = tid & 7, c0 = tid >> 3;
    #pragma unroll
    for (int it = 0; it < 8; ++it) {
      int c = it * 32 + c0;
      float v[4];
      ld4(xin, xbase + (long)c * 16384 + wq * 4, isbf, v);
      #pragma unroll
      for (int r = 0; r < 4; ++r) {
        int m = wq * 4 + r;
        int s = (((m >> 2) ^ m) & 7) << 3;
        int cs = c ^ s;
        bf16_t hi = f2b(v[r]);
        sX[m * 512 + cs] = hi;
        sX[m * 512 + 256 + cs] = f2b(v[r] - b2f(hi));
      }
    }
  }
  __syncthreads();

  // ---- theta = Xhi @ thw ----
  {
    bf16x8 Axf[8];
    #pragma unroll
    for (int t = 0; t < 4; ++t) {
      int tms = t >> 1, tns = (t & 1) * 4 + wv;
      if ((t & 1) == 0) {
        int row = tms * 16 + ln;
        int s = (((row >> 2) ^ row) & 7) << 3;
        #pragma unroll
        for (int c = 0; c < 8; ++c)
          Axf[c] = *(const bf16x8*)(sX + row * 512 + ((c * 32 + kq) ^ s));
      }
      const bf16_t* B = thwb + (tns * 16 + ln) * 256;
      f32x4 a = {0.f,0.f,0.f,0.f};
      #pragma unroll
      for (int c = 0; c < 8; ++c) a = mfma(Axf[c], *(const bf16x8*)(B + c * 32 + kq), a);
      float bias = ldin(thb, tns * 16 + ln, isbf);
      #pragma unroll
      for (int r = 0; r < 4; ++r) {
        float v = a[r] + bias;
        bf16_t hi = f2b(v);
        int mrow = tms * 16 + qd * 4 + r;
        sTh[mrow * LDT + tns * 16 + ln] = hi;
        sTl[mrow * LDT + tns * 16 + ln] = f2b(v - b2f(hi));
      }
    }
  }

  const bf16_t* PH = phiH + (long)tile * 32768;
  const bf16_t* PL = phiL + (long)tile * 32768;
  const bf16_t* GG = gT + (long)tile * 32768;

  uint4 pf0 = *(const uint4*)(PH + tid * 8);
  uint4 pf1 = *(const uint4*)(PH + 2048 + tid * 8);
  uint4 pf2 = *(const uint4*)(PL + tid * 8);
  uint4 pf3 = *(const uint4*)(PL + 2048 + tid * 8);

  // ---- residual extract from swizzled sX (mapping matches wy consumer!) ----
  f32x4 xres[8];
  #pragma unroll
  for (int c4 = 0; c4 < 4; ++c4) {
    #pragma unroll
    for (int jj = 0; jj < 2; ++jj) {
      int o = c4 * 64 + (half * 2 + jj) * 16 + ln;
      f32x4 xr;
      #pragma unroll
      for (int r = 0; r < 4; ++r) {
        int row = m0 + r;
        int s = (((row >> 2) ^ row) & 7) << 3;
        int cs = o ^ s;
        xr[r] = b2f(sX[row * 512 + cs]) + b2f(sX[row * 512 + 256 + cs]);
      }
      xres[c4 * 2 + jj] = xr;
    }
  }
  __syncthreads();

  bf16x8 Ah[4], Al[4];
  {
    const bf16_t* th = sTh + (ms * 16 + ln) * LDT;
    const bf16_t* tl = sTl + (ms * 16 + ln) * LDT;
    #pragma unroll
    for (int c = 0; c < 4; ++c) {
      Ah[c] = *(const bf16x8*)(th + c * 32 + kq);
      Al[c] = *(const bf16x8*)(tl + c * 32 + kq);
    }
  }

  int srow = tid >> 4, scol = (tid & 15) * 8;
  int grow = tid >> 5, gcol = (tid & 31) * 8;

  // ---- S = theta @ phi^T ----
  f32x4 S[8];
  #pragma unroll
  for (int c = 0; c < 8; ++c) {
    *(uint4*)(sPh + srow * LDP + scol) = pf0;
    *(uint4*)(sPh + (srow + 16) * LDP + scol) = pf1;
    *(uint4*)(sPl + srow * LDP + scol) = pf2;
    *(uint4*)(sPl + (srow + 16) * LDP + scol) = pf3;
    if (c < 7) {
      pf0 = *(const uint4*)(PH + (c + 1) * 4096 + tid * 8);
      pf1 = *(const uint4*)(PH + (c + 1) * 4096 + 2048 + tid * 8);
      pf2 = *(const uint4*)(PL + (c + 1) * 4096 + tid * 8);
      pf3 = *(const uint4*)(PL + (c + 1) * 4096 + 2048 + tid * 8);
    } else {
      pf0 = *(const uint4*)(GG + tid * 8);
      pf1 = *(const uint4*)(GG + 2048 + tid * 8);
      pf2 = *(const uint4*)(GG + 4096 + tid * 8);
      pf3 = *(const uint4*)(GG + 6144 + tid * 8);
    }
    __syncthreads();
    const bf16_t* Bh = sPh + (half * 16 + ln) * LDP;
    const bf16_t* Bl = sPl + (half * 16 + ln) * LDP;
    f32x4 a = {0.f,0.f,0.f,0.f};
    #pragma unroll
    for (int kk = 0; kk < 4; ++kk) {
      int ko = kk * 32 + kq;
      bf16x8 bh = *(const bf16x8*)(Bh + ko);
      bf16x8 bl = *(const bf16x8*)(Bl + ko);
      a = mfma(Ah[kk], bl, a);
      a = mfma(Al[kk], bh, a);
      a = mfma(Ah[kk], bh, a);
    }
    S[c] = a;
    __syncthreads();
  }

  // ---- register softmax ----
  float Mr[4], Sr[4], inv4[4];
  #pragma unroll
  for (int r = 0; r < 4; ++r) {
    float m = S[0][r];
    #pragma unroll
    for (int t = 1; t < 8; ++t) m = fmaxf(m, S[t][r]);
    #pragma unroll
    for (int d = 1; d < 16; d <<= 1) m = fmaxf(m, __shfl_xor(m, d, 64));
    Mr[r] = m;
  }
  if (ln == 0) {
    #pragma unroll
    for (int r = 0; r < 4; ++r) sredM[(m0 + r) * 2 + half] = Mr[r];
  }
  __syncthreads();
  #pragma unroll
  for (int r = 0; r < 4; ++r) Mr[r] = fmaxf(Mr[r], sredM[(m0 + r) * 2 + (half ^ 1)]);
  #pragma unroll
  for (int r = 0; r < 4; ++r) {
    float s = 0.f;
    #pragma unroll
    for (int t = 0; t < 8; ++t) { float e = __expf(S[t][r] - Mr[r]); S[t][r] = e; s += e; }
    #pragma unroll
    for (int d = 1; d < 16; d <<= 1) s += __shfl_xor(s, d, 64);
    Sr[r] = s;
  }
  if (ln == 0) {
    #pragma unroll
    for (int r = 0; r < 4; ++r) sredS[(m0 + r) * 2 + half] = Sr[r];
  }
  __syncthreads();
  #pragma unroll
  for (int r = 0; r < 4; ++r) inv4[r] = 1.f / (Sr[r] + sredS[(m0 + r) * 2 + (half ^ 1)]);

  #pragma unroll
  for (int c = 0; c < 8; ++c) {
    int n = c * 32 + half * 16 + ln;
    #pragma unroll
    for (int r = 0; r < 4; ++r)
      sF[(m0 + r) * LDF + n] = f2b(S[c][r] * inv4[r]);
  }
  __syncthreads();

  // ---- y = F @ g ----
  bf16x8 Fa[8];
  {
    const bf16_t* fa = sF + (ms * 16 + ln) * LDF;
    #pragma unroll
    for (int c = 0; c < 8; ++c) Fa[c] = *(const bf16x8*)(fa + c * 32 + kq);
  }
  #pragma unroll
  for (int c = 0; c < 4; ++c) {
    *(uint4*)(sG + grow * LDG + gcol) = pf0;
    *(uint4*)(sG + (grow + 8) * LDG + gcol) = pf1;
    *(uint4*)(sG + (grow + 16) * LDG + gcol) = pf2;
    *(uint4*)(sG + (grow + 24) * LDG + gcol) = pf3;
    if (c < 3) {
      pf0 = *(const uint4*)(GG + (c + 1) * 8192 + tid * 8);
      pf1 = *(const uint4*)(GG + (c + 1) * 8192 + 2048 + tid * 8);
      pf2 = *(const uint4*)(GG + (c + 1) * 8192 + 4096 + tid * 8);
      pf3 = *(const uint4*)(GG + (c + 1) * 8192 + 6144 + tid * 8);
    } else {
      pf0 = *(const uint4*)(wwb + tid * 8);
      pf1 = *(const uint4*)(wwb + 2048 + tid * 8);
      pf2 = *(const uint4*)(wwb + 4096 + tid * 8);
      pf3 = *(const uint4*)(wwb + 6144 + tid * 8);
    }
    __syncthreads();
    const bf16_t* Bg = sG + (half * 16 + ln) * LDG;
    f32x4 a = {0.f,0.f,0.f,0.f};
    #pragma unroll
    for (int kk = 0; kk < 8; ++kk)
      a = mfma(Fa[kk], *(const bf16x8*)(Bg + kk * 32 + kq), a);
    #pragma unroll
    for (int r = 0; r < 4; ++r)
      sY[(m0 + r) * LDT + c * 32 + half * 16 + ln] = f2b(a[r]);
    __syncthreads();
  }

  // ---- wy = y @ ww^T + BN + residual, direct store ----
  bf16x8 Ya[4];
  {
    const bf16_t* ya = sY + (ms * 16 + ln) * LDT;
    #pragma unroll
    for (int kk = 0; kk < 4; ++kk) Ya[kk] = *(const bf16x8*)(ya + kk * 32 + kq);
  }
  #pragma unroll
  for (int cb = 0; cb < 4; ++cb) {
    *(uint4*)(sW + srow * LDP + scol) = pf0;
    *(uint4*)(sW + (srow + 16) * LDP + scol) = pf1;
    *(uint4*)(sW + (srow + 32) * LDP + scol) = pf2;
    *(uint4*)(sW + (srow + 48) * LDP + scol) = pf3;
    if (cb < 3) {
      pf0 = *(const uint4*)(wwb + (cb + 1) * 8192 + tid * 8);
      pf1 = *(const uint4*)(wwb + (cb + 1) * 8192 + 2048 + tid * 8);
      pf2 = *(const uint4*)(wwb + (cb + 1) * 8192 + 4096 + tid * 8);
      pf3 = *(const uint4*)(wwb + (cb + 1) * 8192 + 6144 + tid * 8);
    }
    __syncthreads();
    #pragma unroll
    for (int jj = 0; jj < 2; ++jj) {
      int nsL = half * 2 + jj;
      const bf16_t* B = sW + (nsL * 16 + ln) * LDP;
      f32x4 a = {0.f,0.f,0.f,0.f};
      #pragma unroll
      for (int kk = 0; kk < 4; ++kk)
        a = mfma(Ya[kk], *(const bf16x8*)(B + kk * 32 + kq), a);
      int o = cb * 64 + nsL * 16 + ln;
      float s2 = sc[o], hh = sh[o];
      f32x4 xr = xres[cb * 2 + jj];
      long oi = (long)tile * 262144 + (long)o * 1024 + qb * 32 + m0;
      if (isbf) {
        unsigned short uu[4];
        #pragma unroll
        for (int r = 0; r < 4; ++r) uu[r] = bbits(f2b(a[r] * s2 + hh + xr[r]));
        __builtin_memcpy((unsigned short*)outv + oi, uu, 8);
      } else {
        float vv[4];
        #pragma unroll
        for (int r = 0; r < 4; ++r) vv[r] = a[r] * s2 + hh + xr[r];
        __builtin_memcpy((float*)outv + oi, vv, 16);
      }
    }
    __syncthreads();
  }
}

extern "C" void kernel_launch(void* const* d_in, const int* in_sizes, int n_in,
                              void* d_out, int out_size, void* d_ws, size_t ws_size,
                              hipStream_t stream) {
  (void)in_sizes; (void)n_in; (void)out_size; (void)ws_size;
  const void* x    = d_in[0];
  const void* thwf = d_in[1];
  const void* thb  = d_in[2];
  const void* phw  = d_in[3];
  const void* phb  = d_in[4];
  const void* gwf  = d_in[5];
  const void* gbb  = d_in[6];
  const void* wwf  = d_in[7];
  const void* wb   = d_in[8];
  const void* gma  = d_in[9];
  const void* bta  = d_in[10];
  const void* mn   = d_in[11];
  const void* vr   = d_in[12];

  char* ws = (char*)d_ws;
  bf16_t* thwb = (bf16_t*)(ws);
  bf16_t* phwb = (bf16_t*)(ws + 65536);
  bf16_t* gwb  = (bf16_t*)(ws + 131072);
  bf16_t* wwb  = (bf16_t*)(ws + 196608);
  float*  sc   = (float*)(ws + 262144);
  float*  sh   = (float*)(ws + 263168);
  int*    flag = (int*)(ws + 264192);
  bf16_t* phiH = (bf16_t*)(ws + 264448);
  bf16_t* phiL = (bf16_t*)(ws + 264448 + 8388608);
  bf16_t* gT   = (bf16_t*)(ws + 264448 + 16777216);

  kdetect<<<1, 256, 0, stream>>>((const unsigned int*)x, flag);
  k0<<<128, 256, 0, stream>>>(thwf, phw, gwf, wwf, wb, gma, bta, mn, vr,
                              thwb, phwb, gwb, wwb, sc, sh, flag);
  k1<<<2048, 256, 0, stream>>>(x, phwb, gwb, phb, gbb, phiH, phiL, gT, flag);
  k2<<<4096, 256, 0, stream>>>(x, thwb, thb, phiH, phiL, gT, wwb, sc, sh,
                               d_out, flag);
}